// Round 3
// baseline (964.251 us; speedup 1.0000x reference)
//
#include <hip/hip_runtime.h>
#include <hip/hip_bf16.h>
#include <cstdint>

// EdgeMLP: score = W3 @ sig(W2 @ sig(W1 @ [h1_u,h1_v,h2_u,h2_u] + b1) + b2) + b3
// Factored: z1 = Anode[src] + Bnode[dst]  (A/B stored bf16), where
//   Anode[u] = b1 + W1a @ h1[u] + (W1c+W1d) @ h2[u]
//   Bnode[v] = W1b @ h1[v]
// Node layer: fp32 VALU, weights resident in VGPRs (lane = output col).
// Layer 2: bf16 MFMA 16x16x32. Layer 3 fused fp32 epilogue.

typedef __attribute__((ext_vector_type(8))) short bf16x8;
typedef __attribute__((ext_vector_type(4))) float f32x4;

__device__ __forceinline__ float sigmoidf_(float x) {
    return 1.0f / (1.0f + __expf(-x));
}
__device__ __forceinline__ ushort f2bf(float f) {
    uint32_t u = __float_as_uint(f);
    return (ushort)((u + 0x7fffu + ((u >> 16) & 1u)) >> 16);   // RNE
}
__device__ __forceinline__ float bf2f(ushort h) {
    return __uint_as_float(((uint32_t)h) << 16);
}
__device__ __forceinline__ uint32_t packbf2(float a, float b) {
    return (uint32_t)f2bf(a) | ((uint32_t)f2bf(b) << 16);
}

// ---------- prep: fold/transpose W1 (fp32 [k][j]); W2 -> bf16 MFMA-B frags ----------
__global__ void prep_kernel(const float* __restrict__ W1, const float* __restrict__ W2,
                            float* __restrict__ WA, float* __restrict__ WB,
                            float* __restrict__ WCD, ushort* __restrict__ W2F) {
    int i = blockIdx.x * blockDim.x + threadIdx.x;
    if (i < 8192) {                      // WA/WB/WCD: [k=64][j=128]
        int k = i >> 7, j = i & 127;
        WA[i]  = W1[j * 256 + k];
        WB[i]  = W1[j * 256 + 64 + k];
        WCD[i] = W1[j * 256 + 128 + k] + W1[j * 256 + 192 + k];
    }
    if (i < 16384) {                     // W2F: ((kk*8+nt)*64+lane)*8+j
        int j  = i & 7;
        int lf = (i >> 3) & 63;
        int nt = (i >> 9) & 7;
        int kk = i >> 12;
        int n  = nt * 16 + (lf & 15);
        int kg = kk * 32 + (lf >> 4) * 8 + j;
        W2F[i] = f2bf(W2[n * 128 + kg]);
    }
}

// ---------- node-side: weights in VGPRs, lane = output col, x broadcast ----------
// 6 waves: w0..3 = A-side (WA+WCD), j-half = w&1, node-half = w>>1 (48 nodes)
//          w4..5 = B-side (WB), j-half = w-4, all 96 nodes
__global__ __launch_bounds__(384, 3) void node_kernel(
    const float* __restrict__ h1, const float* __restrict__ h2,
    const float* __restrict__ WA, const float* __restrict__ WB,
    const float* __restrict__ WCD, const float* __restrict__ b1,
    ushort* __restrict__ Aout, ushort* __restrict__ Bout, int N)
{
    const int tid = threadIdx.x;
    const int w = tid >> 6, ln = tid & 63;
    const int nb0 = blockIdx.x * 96;

    if (w < 4) {
        const int jj = ((w & 1) << 6) + ln;
        const int n0 = nb0 + (w >> 1) * 48;
        const int n1 = min(n0 + 48, N);
        float wa[64], wc[64];
        #pragma unroll
        for (int k = 0; k < 64; ++k) { wa[k] = WA[k * 128 + jj]; wc[k] = WCD[k * 128 + jj]; }
        const float bj = b1[jj];
        for (int n = n0; n < n1; ++n) {
            const float4* x1p = (const float4*)(h1 + (size_t)n * 64);
            const float4* x2p = (const float4*)(h2 + (size_t)n * 64);
            float a0 = 0.f, a1 = 0.f, a2 = 0.f, a3 = 0.f;
            #pragma unroll
            for (int i = 0; i < 16; ++i) {
                float4 x = x1p[i];
                a0 = fmaf(wa[4*i],   x.x, a0); a1 = fmaf(wa[4*i+1], x.y, a1);
                a2 = fmaf(wa[4*i+2], x.z, a2); a3 = fmaf(wa[4*i+3], x.w, a3);
            }
            #pragma unroll
            for (int i = 0; i < 16; ++i) {
                float4 x = x2p[i];
                a0 = fmaf(wc[4*i],   x.x, a0); a1 = fmaf(wc[4*i+1], x.y, a1);
                a2 = fmaf(wc[4*i+2], x.z, a2); a3 = fmaf(wc[4*i+3], x.w, a3);
            }
            Aout[(size_t)n * 128 + jj] = f2bf(bj + ((a0 + a1) + (a2 + a3)));
        }
    } else {
        const int jj = ((w - 4) << 6) + ln;
        const int n0 = nb0, n1 = min(nb0 + 96, N);
        float wb[64];
        #pragma unroll
        for (int k = 0; k < 64; ++k) wb[k] = WB[k * 128 + jj];
        for (int n = n0; n < n1; ++n) {
            const float4* xp = (const float4*)(h1 + (size_t)n * 64);
            float a0 = 0.f, a1 = 0.f, a2 = 0.f, a3 = 0.f;
            #pragma unroll
            for (int i = 0; i < 16; ++i) {
                float4 x = xp[i];
                a0 = fmaf(wb[4*i],   x.x, a0); a1 = fmaf(wb[4*i+1], x.y, a1);
                a2 = fmaf(wb[4*i+2], x.z, a2); a3 = fmaf(wb[4*i+3], x.w, a3);
            }
            Bout[(size_t)n * 128 + jj] = f2bf((a0 + a1) + (a2 + a3));
        }
    }
}

// ---------- edge-side: bf16 gather + sigmoid + MFMA layer2 + fused layer3 ----------
__global__ __launch_bounds__(256) void edge_kernel(
    const ushort* __restrict__ Am, const ushort* __restrict__ Bm,
    const int* __restrict__ src, const int* __restrict__ dst,
    const ushort* __restrict__ W2F, const float* __restrict__ b2,
    const float* __restrict__ W3, const float* __restrict__ b3,
    float* __restrict__ out, int E)
{
    __shared__ __align__(16) ushort hlds[64 * 136];   // 17408 B, row stride 272 B
    __shared__ __align__(16) ushort w2f[16384];       // 32768 B: B-frags
    const int tid = threadIdx.x;
    const int g  = tid >> 6;          // wave id: owns edges g*16..g*16+15
    const int ln = tid & 63;
    const int e0 = blockIdx.x * 64;

    // ---- stage W2 fragments into LDS ----
    #pragma unroll
    for (int i = 0; i < 8; ++i)
        ((float4*)w2f)[tid + i * 256] = ((const float4*)W2F)[tid + i * 256];

    // ---- phase 1: gather bf16 A[src]+B[dst], sigmoid, pack into LDS ----
    int us = 0, vs = 0;
    if (ln < 16 && (e0 + g * 16 + ln) < E) {
        us = src[e0 + g * 16 + ln];
        vs = dst[e0 + g * 16 + ln];
    }
    #pragma unroll
    for (int t = 0; t < 16; ++t) {
        if (e0 + g * 16 + t < E) {
            int u = __builtin_amdgcn_readlane(us, t);
            int v = __builtin_amdgcn_readlane(vs, t);
            const ushort2 av = *(const ushort2*)(Am + (size_t)u * 128 + (ln << 1));
            const ushort2 bv = *(const ushort2*)(Bm + (size_t)v * 128 + (ln << 1));
            float z0 = bf2f(av.x) + bf2f(bv.x);
            float z1 = bf2f(av.y) + bf2f(bv.y);
            uint32_t pk = packbf2(sigmoidf_(z0), sigmoidf_(z1));
            *(uint32_t*)&hlds[(g * 16 + t) * 136 + (ln << 1)] = pk;
        }
    }
    __syncthreads();

    // ---- phase 2: wave g computes M16 x N128 x K128 via 32 MFMAs ----
    f32x4 acc[8];
    #pragma unroll
    for (int i = 0; i < 8; ++i)
        #pragma unroll
        for (int r = 0; r < 4; ++r) acc[i][r] = 0.0f;

    const ushort* arow = &hlds[(g * 16 + (ln & 15)) * 136 + (ln >> 4) * 8];
    const ushort* brow = &w2f[ln * 8];
    #pragma unroll
    for (int kk = 0; kk < 4; ++kk) {
        bf16x8 a = *(const bf16x8*)(arow + kk * 32);
        #pragma unroll
        for (int nt = 0; nt < 8; ++nt) {
            bf16x8 b = *(const bf16x8*)(brow + (kk * 8 + nt) * 512);
            acc[nt] = __builtin_amdgcn_mfma_f32_16x16x32_bf16(a, b, acc[nt], 0, 0, 0);
        }
    }

    // ---- epilogue: +b2, sigmoid, dot W3, reduce 16 lanes per quad ----
    float p[4] = {0.f, 0.f, 0.f, 0.f};
    const int nl = ln & 15;
    #pragma unroll
    for (int nt = 0; nt < 8; ++nt) {
        int n = nt * 16 + nl;
        float b2n = b2[n], w3n = W3[n];
        #pragma unroll
        for (int r = 0; r < 4; ++r) {
            float h3 = sigmoidf_(acc[nt][r] + b2n);
            p[r] = fmaf(w3n, h3, p[r]);
        }
    }
    #pragma unroll
    for (int r = 0; r < 4; ++r) {
        p[r] += __shfl_xor(p[r], 1, 16);
        p[r] += __shfl_xor(p[r], 2, 16);
        p[r] += __shfl_xor(p[r], 4, 16);
        p[r] += __shfl_xor(p[r], 8, 16);
    }
    if (nl == 0) {
        const float b3c = b3[0];
        int ebase = e0 + g * 16 + (ln >> 4) * 4;
        #pragma unroll
        for (int r = 0; r < 4; ++r)
            if (ebase + r < E) out[ebase + r] = p[r] + b3c;
    }
}

// ---------- fallback (only if workspace too small) ----------
__global__ void naive_kernel(
    const float* __restrict__ h1, const float* __restrict__ h2,
    const int* __restrict__ src, const int* __restrict__ dst,
    const float* __restrict__ W1, const float* __restrict__ b1,
    const float* __restrict__ W2, const float* __restrict__ b2,
    const float* __restrict__ W3, const float* __restrict__ b3,
    float* __restrict__ out, int E, int N)
{
    int e = blockIdx.x * blockDim.x + threadIdx.x;
    if (e >= E) return;
    int u = src[e], v = dst[e];
    float h[128];
    for (int j = 0; j < 128; ++j) {
        float z = b1[j];
        const float* wj = W1 + j * 256;
        for (int k = 0; k < 64; ++k) {
            z += wj[k] * h1[(size_t)u * 64 + k]
               + wj[64 + k] * h1[(size_t)v * 64 + k]
               + (wj[128 + k] + wj[192 + k]) * h2[(size_t)u * 64 + k];
        }
        h[j] = sigmoidf_(z);
    }
    float gg[128];
    for (int j = 0; j < 128; ++j) {
        float z = b2[j];
        for (int k = 0; k < 128; ++k) z = fmaf(W2[j * 128 + k], h[k], z);
        gg[j] = sigmoidf_(z);
    }
    float s = b3[0];
    for (int j = 0; j < 128; ++j) s = fmaf(W3[j], gg[j], s);
    out[e] = s;
}

extern "C" void kernel_launch(void* const* d_in, const int* in_sizes, int n_in,
                              void* d_out, int out_size, void* d_ws, size_t ws_size,
                              hipStream_t stream) {
    const float* h1 = (const float*)d_in[0];
    const float* h2 = (const float*)d_in[1];
    const int*  src = (const int*)d_in[2];
    const int*  dst = (const int*)d_in[3];
    const float* W1 = (const float*)d_in[4];
    const float* b1 = (const float*)d_in[5];
    const float* W2 = (const float*)d_in[6];
    const float* b2 = (const float*)d_in[7];
    const float* W3 = (const float*)d_in[8];
    const float* b3 = (const float*)d_in[9];
    float* out = (float*)d_out;

    const int N = in_sizes[0] / 64;
    const int E = in_sizes[2];

    // workspace layout (float units; A/B are bf16 so N*128 ushorts = N*64 floats)
    size_t offA   = 0;
    size_t offB   = offA + (size_t)N * 64;
    size_t offWA  = offB + (size_t)N * 64;
    size_t offWB  = offWA + 8192;
    size_t offWCD = offWB + 8192;
    size_t offW2F = offWCD + 8192;            // 16384 ushorts = 8192 floats
    size_t totalF = offW2F + 8192;

    if (ws_size < totalF * sizeof(float)) {
        naive_kernel<<<(E + 255) / 256, 256, 0, stream>>>(
            h1, h2, src, dst, W1, b1, W2, b2, W3, b3, out, E, N);
        return;
    }

    float* ws = (float*)d_ws;
    prep_kernel<<<64, 256, 0, stream>>>(W1, W2, ws + offWA, ws + offWB,
                                        ws + offWCD, (ushort*)(ws + offW2F));
    node_kernel<<<(N + 95) / 96, 384, 0, stream>>>(
        h1, h2, ws + offWA, ws + offWB, ws + offWCD, b1,
        (ushort*)(ws + offA), (ushort*)(ws + offB), N);
    edge_kernel<<<(E + 63) / 64, 256, 0, stream>>>(
        (const ushort*)(ws + offA), (const ushort*)(ws + offB), src, dst,
        (const ushort*)(ws + offW2F), b2, W3, b3, out, E);
}

// Round 4
// 174.599 us; speedup vs baseline: 5.5227x; 5.5227x over previous
//
#include <hip/hip_runtime.h>
#include <hip/hip_bf16.h>
#include <cstdint>

// EdgeMLP: score = W3 @ sig(W2 @ sig(W1 @ [h1_u,h1_v,h2_u,h2_u] + b1) + b2) + b3
// Factored: z1 = Anode[src] + Bnode[dst]  (A/B stored bf16), where
//   [Aout|Bout] = bf16(X) @ [WCF | WBF],  X = [h1|h2] (K=128; WBF uses only h1 half)
// Node layer: bf16 MFMA (16x16x32), weights as B-frags straight from global (L2-hot).
// Edge layer 2: bf16 MFMA with per-wave register-resident B-frags (n-quarter split).

typedef __attribute__((ext_vector_type(8))) short bf16x8;
typedef __attribute__((ext_vector_type(4))) float f32x4;

__device__ __forceinline__ float sigmoidf_(float x) {
    return 1.0f / (1.0f + __expf(-x));
}
__device__ __forceinline__ ushort f2bf(float f) {
    uint32_t u = __float_as_uint(f);
    return (ushort)((u + 0x7fffu + ((u >> 16) & 1u)) >> 16);   // RNE
}
__device__ __forceinline__ float bf2f(ushort h) {
    return __uint_as_float(((uint32_t)h) << 16);
}
__device__ __forceinline__ uint32_t packbf2(float a, float b) {
    return (uint32_t)f2bf(a) | ((uint32_t)f2bf(b) << 16);
}

// ---------- prep: all weights -> bf16 MFMA B-fragment layout ----------
// frag idx: ((kk*8+nt)*64+lane)*8 + j ; n = nt*16+(lane&15) ; k = kk*32+(lane>>4)*8+j
__global__ void prep_kernel(const float* __restrict__ W1, const float* __restrict__ W2,
                            ushort* __restrict__ WCF, ushort* __restrict__ WBF,
                            ushort* __restrict__ W2F) {
    int i = blockIdx.x * blockDim.x + threadIdx.x;
    if (i >= 16384) return;
    int j = i & 7, lf = (i >> 3) & 63, nt = (i >> 9) & 7, kk = i >> 12;
    int n = nt * 16 + (lf & 15);
    int k = kk * 32 + ((lf >> 4) << 3) + j;
    W2F[i] = f2bf(W2[n * 128 + k]);
    float v = (k < 64) ? W1[n * 256 + k]
                       : W1[n * 256 + 128 + (k - 64)] + W1[n * 256 + 192 + (k - 64)];
    WCF[i] = f2bf(v);
    if (kk < 2) WBF[i] = f2bf(W1[n * 256 + 64 + k]);   // K=64: h1-half only
}

// ---------- node-side: MFMA GEMM, 64 nodes/block ----------
__global__ __launch_bounds__(256, 3) void node_kernel(
    const float* __restrict__ h1, const float* __restrict__ h2,
    const ushort* __restrict__ WCF, const ushort* __restrict__ WBF,
    const float* __restrict__ b1,
    ushort* __restrict__ Aout, ushort* __restrict__ Bout, int N)
{
    __shared__ __align__(16) ushort xt[64 * 136];   // [node][k] bf16, stride 136
    const int tid = threadIdx.x, g = tid >> 6, ln = tid & 63;
    const int n0 = blockIdx.x * 64;

    // stage X = [h1|h2] rows as bf16
    #pragma unroll
    for (int i = 0; i < 8; ++i) {
        int local = i * 256 + tid;          // 2048 float4-groups
        int node = local >> 5;
        int kq = (local & 31) * 4;
        float4 x = make_float4(0.f, 0.f, 0.f, 0.f);
        if (n0 + node < N)
            x = (kq < 64) ? *(const float4*)(h1 + (size_t)(n0 + node) * 64 + kq)
                          : *(const float4*)(h2 + (size_t)(n0 + node) * 64 + (kq - 64));
        ushort4 p = make_ushort4(f2bf(x.x), f2bf(x.y), f2bf(x.z), f2bf(x.w));
        *(ushort4*)&xt[node * 136 + kq] = p;
    }
    __syncthreads();

    const ushort* arow = &xt[(g * 16 + (ln & 15)) * 136 + ((ln >> 4) << 3)];
    f32x4 accA[8], accB[8];
    #pragma unroll
    for (int i = 0; i < 8; ++i)
        #pragma unroll
        for (int r = 0; r < 4; ++r) { accA[i][r] = 0.f; accB[i][r] = 0.f; }

    #pragma unroll
    for (int kk = 0; kk < 4; ++kk) {
        bf16x8 a = *(const bf16x8*)(arow + kk * 32);
        #pragma unroll
        for (int nt = 0; nt < 8; ++nt) {
            bf16x8 b = *(const bf16x8*)(WCF + (((kk * 8 + nt) * 64 + ln) << 3));
            accA[nt] = __builtin_amdgcn_mfma_f32_16x16x32_bf16(a, b, accA[nt], 0, 0, 0);
        }
        if (kk < 2) {
            #pragma unroll
            for (int nt = 0; nt < 8; ++nt) {
                bf16x8 b = *(const bf16x8*)(WBF + (((kk * 8 + nt) * 64 + ln) << 3));
                accB[nt] = __builtin_amdgcn_mfma_f32_16x16x32_bf16(a, b, accB[nt], 0, 0, 0);
            }
        }
    }

    // epilogue: C/D col = n-col (j), row = node-within-16
    const int nl = ln & 15, q = ln >> 4;
    #pragma unroll
    for (int nt = 0; nt < 8; ++nt) {
        int j = nt * 16 + nl;
        float b1j = b1[j];
        #pragma unroll
        for (int r = 0; r < 4; ++r) {
            int node = n0 + g * 16 + q * 4 + r;
            if (node < N) {
                Aout[(size_t)node * 128 + j] = f2bf(accA[nt][r] + b1j);
                Bout[(size_t)node * 128 + j] = f2bf(accB[nt][r]);
            }
        }
    }
}

// ---------- edge-side: gather + sigmoid + MFMA layer2 (reg B-frags) + layer3 ----------
__global__ __launch_bounds__(256, 4) void edge_kernel(
    const ushort* __restrict__ Am, const ushort* __restrict__ Bm,
    const int* __restrict__ src, const int* __restrict__ dst,
    const ushort* __restrict__ W2F, const float* __restrict__ b2,
    const float* __restrict__ W3, const float* __restrict__ b3,
    float* __restrict__ out, int E, int ntiles)
{
    __shared__ __align__(16) ushort hlds[64 * 136];   // 17408 B
    __shared__ float part[4 * 64];                    // 1 KB partial scores
    const int tid = threadIdx.x, g = tid >> 6, ln = tid & 63;
    const int nl = ln & 15, q = ln >> 4;

    // preload this wave's n-quarter B-frags (cols g*32..g*32+31, K=128) -> 32 VGPRs
    bf16x8 bfrag[8];
    #pragma unroll
    for (int kk = 0; kk < 4; ++kk)
        #pragma unroll
        for (int nt = 0; nt < 2; ++nt)
            bfrag[kk * 2 + nt] =
                *(const bf16x8*)(W2F + (((kk * 8 + g * 2 + nt) * 64 + ln) << 3));

    float b2c[2], w3c[2];
    #pragma unroll
    for (int nt = 0; nt < 2; ++nt) {
        int n = g * 32 + nt * 16 + nl;
        b2c[nt] = b2[n]; w3c[nt] = W3[n];
    }
    const float b3c = b3[0];

    for (int tile = blockIdx.x; tile < ntiles; tile += gridDim.x) {
        const int e0 = tile * 64;
        __syncthreads();   // hlds/part reuse safety (prev iter consumers done)

        // ---- phase 1: wave g gathers edges e0+g*16 .. +15 ----
        int us = 0, vs = 0;
        const int eb = e0 + g * 16;
        if (ln < 16 && eb + ln < E) { us = src[eb + ln]; vs = dst[eb + ln]; }
        #pragma unroll 4
        for (int t = 0; t < 16; ++t) {
            if (eb + t < E) {
                int u = __builtin_amdgcn_readlane(us, t);
                int v = __builtin_amdgcn_readlane(vs, t);
                ushort2 av = *(const ushort2*)(Am + (size_t)u * 128 + (ln << 1));
                ushort2 bv = *(const ushort2*)(Bm + (size_t)v * 128 + (ln << 1));
                uint32_t pk = packbf2(sigmoidf_(bf2f(av.x) + bf2f(bv.x)),
                                      sigmoidf_(bf2f(av.y) + bf2f(bv.y)));
                *(uint32_t*)&hlds[(g * 16 + t) * 136 + (ln << 1)] = pk;
            }
        }
        __syncthreads();

        // ---- phase 2: all 4 m-tiles, this wave's n-quarter ----
        #pragma unroll
        for (int m = 0; m < 4; ++m) {
            f32x4 acc[2];
            #pragma unroll
            for (int r = 0; r < 4; ++r) { acc[0][r] = 0.f; acc[1][r] = 0.f; }
            const ushort* arow = &hlds[(m * 16 + nl) * 136 + (q << 3)];
            #pragma unroll
            for (int kk = 0; kk < 4; ++kk) {
                bf16x8 a = *(const bf16x8*)(arow + kk * 32);
                acc[0] = __builtin_amdgcn_mfma_f32_16x16x32_bf16(a, bfrag[kk * 2],     acc[0], 0, 0, 0);
                acc[1] = __builtin_amdgcn_mfma_f32_16x16x32_bf16(a, bfrag[kk * 2 + 1], acc[1], 0, 0, 0);
            }
            float p[4] = {0.f, 0.f, 0.f, 0.f};
            #pragma unroll
            for (int nt = 0; nt < 2; ++nt)
                #pragma unroll
                for (int r = 0; r < 4; ++r)
                    p[r] = fmaf(w3c[nt], sigmoidf_(acc[nt][r] + b2c[nt]), p[r]);
            #pragma unroll
            for (int r = 0; r < 4; ++r) {
                p[r] += __shfl_xor(p[r], 1, 16);
                p[r] += __shfl_xor(p[r], 2, 16);
                p[r] += __shfl_xor(p[r], 4, 16);
                p[r] += __shfl_xor(p[r], 8, 16);
            }
            if (nl == 0) {
                #pragma unroll
                for (int r = 0; r < 4; ++r)
                    part[g * 64 + m * 16 + q * 4 + r] = p[r];
            }
        }
        __syncthreads();
        if (tid < 64 && e0 + tid < E)
            out[e0 + tid] = part[tid] + part[64 + tid] + part[128 + tid]
                          + part[192 + tid] + b3c;
    }
}

// ---------- fallback (only if workspace too small) ----------
__global__ void naive_kernel(
    const float* __restrict__ h1, const float* __restrict__ h2,
    const int* __restrict__ src, const int* __restrict__ dst,
    const float* __restrict__ W1, const float* __restrict__ b1,
    const float* __restrict__ W2, const float* __restrict__ b2,
    const float* __restrict__ W3, const float* __restrict__ b3,
    float* __restrict__ out, int E, int N)
{
    int e = blockIdx.x * blockDim.x + threadIdx.x;
    if (e >= E) return;
    int u = src[e], v = dst[e];
    float h[128];
    for (int j = 0; j < 128; ++j) {
        float z = b1[j];
        const float* wj = W1 + j * 256;
        for (int k = 0; k < 64; ++k) {
            z += wj[k] * h1[(size_t)u * 64 + k]
               + wj[64 + k] * h1[(size_t)v * 64 + k]
               + (wj[128 + k] + wj[192 + k]) * h2[(size_t)u * 64 + k];
        }
        h[j] = sigmoidf_(z);
    }
    float gg[128];
    for (int j = 0; j < 128; ++j) {
        float z = b2[j];
        for (int k = 0; k < 128; ++k) z = fmaf(W2[j * 128 + k], h[k], z);
        gg[j] = sigmoidf_(z);
    }
    float s = b3[0];
    for (int j = 0; j < 128; ++j) s = fmaf(W3[j], gg[j], s);
    out[e] = s;
}

extern "C" void kernel_launch(void* const* d_in, const int* in_sizes, int n_in,
                              void* d_out, int out_size, void* d_ws, size_t ws_size,
                              hipStream_t stream) {
    const float* h1 = (const float*)d_in[0];
    const float* h2 = (const float*)d_in[1];
    const int*  src = (const int*)d_in[2];
    const int*  dst = (const int*)d_in[3];
    const float* W1 = (const float*)d_in[4];
    const float* b1 = (const float*)d_in[5];
    const float* W2 = (const float*)d_in[6];
    const float* b2 = (const float*)d_in[7];
    const float* W3 = (const float*)d_in[8];
    const float* b3 = (const float*)d_in[9];
    float* out = (float*)d_out;

    const int N = in_sizes[0] / 64;
    const int E = in_sizes[2];

    // workspace layout (float units)
    size_t offA   = 0;                         // N*128 ushorts
    size_t offB   = offA + (size_t)N * 64;     // N*128 ushorts
    size_t offWCF = offB + (size_t)N * 64;     // 16384 ushorts
    size_t offWBF = offWCF + 8192;             // 8192 ushorts
    size_t offW2F = offWBF + 4096;             // 16384 ushorts
    size_t totalF = offW2F + 8192;

    if (ws_size < totalF * sizeof(float)) {
        naive_kernel<<<(E + 255) / 256, 256, 0, stream>>>(
            h1, h2, src, dst, W1, b1, W2, b2, W3, b3, out, E, N);
        return;
    }

    float* ws = (float*)d_ws;
    ushort* WCF = (ushort*)(ws + offWCF);
    ushort* WBF = (ushort*)(ws + offWBF);
    ushort* W2F = (ushort*)(ws + offW2F);

    prep_kernel<<<64, 256, 0, stream>>>(W1, W2, WCF, WBF, W2F);
    node_kernel<<<(N + 63) / 64, 256, 0, stream>>>(
        h1, h2, WCF, WBF, b1, (ushort*)(ws + offA), (ushort*)(ws + offB), N);
    const int ntiles = (E + 63) / 64;
    edge_kernel<<<1024, 256, 0, stream>>>(
        (const ushort*)(ws + offA), (const ushort*)(ws + offB), src, dst,
        W2F, b2, W3, b3, out, E, ntiles);
}

// Round 5
// 137.220 us; speedup vs baseline: 7.0270x; 1.2724x over previous
//
#include <hip/hip_runtime.h>
#include <hip/hip_bf16.h>
#include <cstdint>

// EdgeMLP: score = W3 @ sig(W2 @ sig(W1 @ [h1_u,h1_v,h2_u,h2_u] + b1) + b2) + b3
// Factored: z1 = Anode[src] + Bnode[dst]  (A/B stored bf16, PERMUTED col order:
//   dword slot d of a row holds true cols (32*(d>>4) + (d&15), +16) as (lo,hi);
//   the permutation is compensated in W2F's k-index in prep).
// Node layer: bf16 MFMA, weight frags register-resident per wave n-quarter,
//   epilogue stores packed dwords straight from C/D layout (coalesced, no LDS).
// Edge layer 2: bf16 MFMA, register B-frags; sigmoid = mul+exp+add+rcp (raw v_rcp).

typedef __attribute__((ext_vector_type(8))) short bf16x8;
typedef __attribute__((ext_vector_type(4))) float f32x4;

__device__ __forceinline__ float sigmoid_fast(float x) {
    float e = __expf(-x);                       // v_mul + v_exp
    return __builtin_amdgcn_rcpf(1.0f + e);     // v_add + v_rcp  (~1 ulp)
}
__device__ __forceinline__ ushort f2bf_rne(float f) {      // prep path only
    uint32_t u = __float_as_uint(f);
    return (ushort)((u + 0x7fffu + ((u >> 16) & 1u)) >> 16);
}
__device__ __forceinline__ float bf2f_lo(uint32_t d) { return __uint_as_float(d << 16); }
__device__ __forceinline__ float bf2f_hi(uint32_t d) { return __uint_as_float(d & 0xffff0000u); }
__device__ __forceinline__ uint32_t packbf_rhu(float x, float y) {   // round-half-up
    return ((__float_as_uint(x) + 0x8000u) >> 16) |
           ((__float_as_uint(y) + 0x8000u) & 0xffff0000u);
}

// ---------- prep: weights -> bf16 MFMA B-fragment layouts ----------
// frag idx: ((kk*8+nt)*64+lane)*8 + j ; n = nt*16+(lane&15) ; kpos = kk*32+(lane>>4)*8+j
// WCF/WBF use true k = kpos (node X staged in true order).
// W2F uses permuted ktrue to match the A/B dword-pair column packing.
__global__ void prep_kernel(const float* __restrict__ W1, const float* __restrict__ W2,
                            ushort* __restrict__ WCF, ushort* __restrict__ WBF,
                            ushort* __restrict__ W2F) {
    int i = blockIdx.x * blockDim.x + threadIdx.x;
    if (i >= 16384) return;
    int j = i & 7, lf = (i >> 3) & 63, nt = (i >> 9) & 7, kk = i >> 12;
    int n = nt * 16 + (lf & 15);
    int kpos = kk * 32 + ((lf >> 4) << 3) + j;
    int ktrue = (kpos & ~31) | ((kpos >> 1) & 15) | ((kpos & 1) << 4);
    W2F[i] = f2bf_rne(W2[n * 128 + ktrue]);
    float v = (kpos < 64) ? W1[n * 256 + kpos]
                          : W1[n * 256 + 128 + (kpos - 64)] + W1[n * 256 + 192 + (kpos - 64)];
    WCF[i] = f2bf_rne(v);
    if (kk < 2) WBF[i] = f2bf_rne(W1[n * 256 + 64 + kpos]);   // K=64: h1-half only
}

// ---------- node-side: MFMA, register weight frags, direct coalesced stores ----------
__global__ __launch_bounds__(256, 4) void node_kernel(
    const float* __restrict__ h1, const float* __restrict__ h2,
    const ushort* __restrict__ WCF, const ushort* __restrict__ WBF,
    const float* __restrict__ b1,
    uint32_t* __restrict__ Aout, uint32_t* __restrict__ Bout, int N)
{
    __shared__ __align__(16) ushort xt[64 * 136];   // [node][k true order]
    const int tid = threadIdx.x, g = tid >> 6, ln = tid & 63;
    const int nl = ln & 15, q = ln >> 4;
    const int n0 = blockIdx.x * 64;

    // wave g owns n-cols [g*32, g*32+32): 12 weight frags -> 48 VGPRs
    bf16x8 fa[4][2], fb[2][2];
    #pragma unroll
    for (int kk = 0; kk < 4; ++kk)
        #pragma unroll
        for (int nt = 0; nt < 2; ++nt)
            fa[kk][nt] = *(const bf16x8*)(WCF + (((kk * 8 + g * 2 + nt) * 64 + ln) << 3));
    #pragma unroll
    for (int kk = 0; kk < 2; ++kk)
        #pragma unroll
        for (int nt = 0; nt < 2; ++nt)
            fb[kk][nt] = *(const bf16x8*)(WBF + (((kk * 8 + g * 2 + nt) * 64 + ln) << 3));
    const float b1c0 = b1[g * 32 + nl], b1c1 = b1[g * 32 + 16 + nl];

    // stage X = [h1|h2] as bf16 (true k order)
    #pragma unroll
    for (int i = 0; i < 8; ++i) {
        int local = i * 256 + tid;
        int node = local >> 5;
        int kq = (local & 31) * 4;
        float4 x = make_float4(0.f, 0.f, 0.f, 0.f);
        if (n0 + node < N)
            x = (kq < 64) ? *(const float4*)(h1 + (size_t)(n0 + node) * 64 + kq)
                          : *(const float4*)(h2 + (size_t)(n0 + node) * 64 + (kq - 64));
        uint32_t d0 = packbf_rhu(x.x, x.y), d1 = packbf_rhu(x.z, x.w);
        *(uint2*)&xt[node * 136 + kq] = make_uint2(d0, d1);
    }
    __syncthreads();

    #pragma unroll
    for (int m = 0; m < 4; ++m) {
        f32x4 accA[2], accB[2];
        #pragma unroll
        for (int r = 0; r < 4; ++r) { accA[0][r] = accA[1][r] = accB[0][r] = accB[1][r] = 0.f; }
        const ushort* arow = &xt[(m * 16 + nl) * 136 + (q << 3)];
        #pragma unroll
        for (int kk = 0; kk < 4; ++kk) {
            bf16x8 a = *(const bf16x8*)(arow + kk * 32);
            accA[0] = __builtin_amdgcn_mfma_f32_16x16x32_bf16(a, fa[kk][0], accA[0], 0, 0, 0);
            accA[1] = __builtin_amdgcn_mfma_f32_16x16x32_bf16(a, fa[kk][1], accA[1], 0, 0, 0);
            if (kk < 2) {
                accB[0] = __builtin_amdgcn_mfma_f32_16x16x32_bf16(a, fb[kk][0], accB[0], 0, 0, 0);
                accB[1] = __builtin_amdgcn_mfma_f32_16x16x32_bf16(a, fb[kk][1], accB[1], 0, 0, 0);
            }
        }
        // C/D: node = m*16 + q*4 + r, cols (g*32+nl, g*32+16+nl) -> dword slot g*16+nl
        #pragma unroll
        for (int r = 0; r < 4; ++r) {
            int node = n0 + m * 16 + q * 4 + r;
            if (node < N) {
                uint32_t da = packbf_rhu(accA[0][r] + b1c0, accA[1][r] + b1c1);
                uint32_t db = packbf_rhu(accB[0][r], accB[1][r]);
                Aout[(size_t)node * 64 + g * 16 + nl] = da;
                Bout[(size_t)node * 64 + g * 16 + nl] = db;
            }
        }
    }
}

// ---------- edge-side: gather + sigmoid + MFMA layer2 + fused layer3 ----------
__global__ __launch_bounds__(256, 4) void edge_kernel(
    const uint32_t* __restrict__ Am, const uint32_t* __restrict__ Bm,
    const int* __restrict__ src, const int* __restrict__ dst,
    const ushort* __restrict__ W2F, const float* __restrict__ b2,
    const float* __restrict__ W3, const float* __restrict__ b3,
    float* __restrict__ out, int E, int ntiles)
{
    __shared__ __align__(16) ushort hlds[64 * 136];   // 17408 B
    __shared__ float part[4 * 64];
    const int tid = threadIdx.x, g = tid >> 6, ln = tid & 63;
    const int nl = ln & 15, q = ln >> 4;
    const int sub = ln >> 5, c = ln & 31;             // 2-edge gather split

    // register B-frags: this wave's n-quarter (cols g*32..+31), K=128
    bf16x8 bfrag[8];
    #pragma unroll
    for (int kk = 0; kk < 4; ++kk)
        #pragma unroll
        for (int nt = 0; nt < 2; ++nt)
            bfrag[kk * 2 + nt] =
                *(const bf16x8*)(W2F + (((kk * 8 + g * 2 + nt) * 64 + ln) << 3));
    float b2c[2], w3c[2];
    #pragma unroll
    for (int nt = 0; nt < 2; ++nt) {
        int n = g * 32 + nt * 16 + nl;
        b2c[nt] = b2[n]; w3c[nt] = W3[n];
    }
    const float b3c = b3[0];

    for (int tile = blockIdx.x; tile < ntiles; tile += gridDim.x) {
        const int e0 = tile * 64;
        const int eb = e0 + g * 16;
        __syncthreads();   // prev iter's part-readers / hlds-readers done

        // ---- phase 1: 16 edges per wave, 2 edges per iteration ----
        int us = 0, vs = 0;
        if (ln < 16 && eb + ln < E) { us = src[eb + ln]; vs = dst[eb + ln]; }
        #pragma unroll
        for (int t = 0; t < 8; ++t) {
            int u0 = __builtin_amdgcn_readlane(us, 2 * t);
            int u1 = __builtin_amdgcn_readlane(us, 2 * t + 1);
            int v0 = __builtin_amdgcn_readlane(vs, 2 * t);
            int v1 = __builtin_amdgcn_readlane(vs, 2 * t + 1);
            int uu = sub ? u1 : u0;
            int vv = sub ? v1 : v0;
            uint2 av = *(const uint2*)(Am + (size_t)uu * 64 + 2 * c);
            uint2 bv = *(const uint2*)(Bm + (size_t)vv * 64 + 2 * c);
            float s0 = sigmoid_fast(bf2f_lo(av.x) + bf2f_lo(bv.x));
            float s1 = sigmoid_fast(bf2f_hi(av.x) + bf2f_hi(bv.x));
            float s2 = sigmoid_fast(bf2f_lo(av.y) + bf2f_lo(bv.y));
            float s3 = sigmoid_fast(bf2f_hi(av.y) + bf2f_hi(bv.y));
            uint32_t d0 = packbf_rhu(s0, s1), d1 = packbf_rhu(s2, s3);
            *(uint2*)&hlds[(g * 16 + 2 * t + sub) * 136 + c * 4] = make_uint2(d0, d1);
        }
        __syncthreads();

        // ---- phase 2: all 4 m-tiles, this wave's n-quarter ----
        #pragma unroll
        for (int m = 0; m < 4; ++m) {
            f32x4 acc[2];
            #pragma unroll
            for (int r = 0; r < 4; ++r) { acc[0][r] = 0.f; acc[1][r] = 0.f; }
            const ushort* arow = &hlds[(m * 16 + nl) * 136 + (q << 3)];
            #pragma unroll
            for (int kk = 0; kk < 4; ++kk) {
                bf16x8 a = *(const bf16x8*)(arow + kk * 32);
                acc[0] = __builtin_amdgcn_mfma_f32_16x16x32_bf16(a, bfrag[kk * 2],     acc[0], 0, 0, 0);
                acc[1] = __builtin_amdgcn_mfma_f32_16x16x32_bf16(a, bfrag[kk * 2 + 1], acc[1], 0, 0, 0);
            }
            float p[4] = {0.f, 0.f, 0.f, 0.f};
            #pragma unroll
            for (int nt = 0; nt < 2; ++nt)
                #pragma unroll
                for (int r = 0; r < 4; ++r)
                    p[r] = fmaf(w3c[nt], sigmoid_fast(acc[nt][r] + b2c[nt]), p[r]);
            #pragma unroll
            for (int r = 0; r < 4; ++r) {
                p[r] += __shfl_xor(p[r], 1, 16);
                p[r] += __shfl_xor(p[r], 2, 16);
                p[r] += __shfl_xor(p[r], 4, 16);
                p[r] += __shfl_xor(p[r], 8, 16);
            }
            if (nl == 0) {
                #pragma unroll
                for (int r = 0; r < 4; ++r)
                    part[g * 64 + m * 16 + q * 4 + r] = p[r];
            }
        }
        __syncthreads();
        if (tid < 64 && e0 + tid < E)
            out[e0 + tid] = (part[tid] + part[64 + tid])
                          + (part[128 + tid] + part[192 + tid]) + b3c;
    }
}

// ---------- fallback (only if workspace too small) ----------
__global__ void naive_kernel(
    const float* __restrict__ h1, const float* __restrict__ h2,
    const int* __restrict__ src, const int* __restrict__ dst,
    const float* __restrict__ W1, const float* __restrict__ b1,
    const float* __restrict__ W2, const float* __restrict__ b2,
    const float* __restrict__ W3, const float* __restrict__ b3,
    float* __restrict__ out, int E, int N)
{
    int e = blockIdx.x * blockDim.x + threadIdx.x;
    if (e >= E) return;
    int u = src[e], v = dst[e];
    float h[128];
    for (int j = 0; j < 128; ++j) {
        float z = b1[j];
        const float* wj = W1 + j * 256;
        for (int k = 0; k < 64; ++k) {
            z += wj[k] * h1[(size_t)u * 64 + k]
               + wj[64 + k] * h1[(size_t)v * 64 + k]
               + (wj[128 + k] + wj[192 + k]) * h2[(size_t)u * 64 + k];
        }
        h[j] = 1.0f / (1.0f + __expf(-z));
    }
    float gg[128];
    for (int j = 0; j < 128; ++j) {
        float z = b2[j];
        for (int k = 0; k < 128; ++k) z = fmaf(W2[j * 128 + k], h[k], z);
        gg[j] = 1.0f / (1.0f + __expf(-z));
    }
    float s = b3[0];
    for (int j = 0; j < 128; ++j) s = fmaf(W3[j], gg[j], s);
    out[e] = s;
}

extern "C" void kernel_launch(void* const* d_in, const int* in_sizes, int n_in,
                              void* d_out, int out_size, void* d_ws, size_t ws_size,
                              hipStream_t stream) {
    const float* h1 = (const float*)d_in[0];
    const float* h2 = (const float*)d_in[1];
    const int*  src = (const int*)d_in[2];
    const int*  dst = (const int*)d_in[3];
    const float* W1 = (const float*)d_in[4];
    const float* b1 = (const float*)d_in[5];
    const float* W2 = (const float*)d_in[6];
    const float* b2 = (const float*)d_in[7];
    const float* W3 = (const float*)d_in[8];
    const float* b3 = (const float*)d_in[9];
    float* out = (float*)d_out;

    const int N = in_sizes[0] / 64;
    const int E = in_sizes[2];

    // workspace layout (float units)
    size_t offA   = 0;                         // N*64 dwords (bf16-pair packed)
    size_t offB   = offA + (size_t)N * 64;
    size_t offWCF = offB + (size_t)N * 64;     // 16384 ushorts
    size_t offWBF = offWCF + 8192;             // 8192 ushorts
    size_t offW2F = offWBF + 4096;             // 16384 ushorts
    size_t totalF = offW2F + 8192;

    if (ws_size < totalF * sizeof(float)) {
        naive_kernel<<<(E + 255) / 256, 256, 0, stream>>>(
            h1, h2, src, dst, W1, b1, W2, b2, W3, b3, out, E, N);
        return;
    }

    float* ws = (float*)d_ws;
    ushort* WCF = (ushort*)(ws + offWCF);
    ushort* WBF = (ushort*)(ws + offWBF);
    ushort* W2F = (ushort*)(ws + offW2F);

    prep_kernel<<<64, 256, 0, stream>>>(W1, W2, WCF, WBF, W2F);
    node_kernel<<<(N + 63) / 64, 256, 0, stream>>>(
        h1, h2, WCF, WBF, b1, (uint32_t*)(ws + offA), (uint32_t*)(ws + offB), N);
    const int ntiles = (E + 63) / 64;
    edge_kernel<<<1000, 256, 0, stream>>>(
        (const uint32_t*)(ws + offA), (const uint32_t*)(ws + offB), src, dst,
        W2F, b2, W3, b3, out, E, ntiles);
}

// Round 7
// 130.806 us; speedup vs baseline: 7.3716x; 1.0490x over previous
//
#include <hip/hip_runtime.h>
#include <hip/hip_bf16.h>
#include <cstdint>

// EdgeMLP: score = W3 @ sig(W2 @ sig(W1 @ [h1_u,h1_v,h2_u,h2_u] + b1) + b2) + b3
// Factored: z1 = Anode[src] + Bnode[dst]  (A/B stored bf16, PERMUTED col order:
//   dword slot d of a row holds true cols (32*(d>>4) + (d&15), +16) as (lo,hi);
//   the permutation is compensated in W2F's k-index in prep).
// Node layer: bf16 MFMA, weight frags register-resident per wave n-quarter.
// Edge layer 2: bf16 MFMA, register B-frags, single-barrier double-buffered
//   pipeline; gather = 4 lanes/edge uint4 loads (independent, latency-overlapped).
// R6 bug (fixed): gather base must be t*64 + g*16 — each wave gathers ITS 16 edges.

typedef __attribute__((ext_vector_type(8))) short bf16x8;
typedef __attribute__((ext_vector_type(4))) float f32x4;

__device__ __forceinline__ float sigmoid_fast(float x) {
    float e = __expf(-x);                       // v_mul + v_exp
    return __builtin_amdgcn_rcpf(1.0f + e);     // v_add + v_rcp  (~1 ulp)
}
__device__ __forceinline__ ushort f2bf_rne(float f) {      // prep path only
    uint32_t u = __float_as_uint(f);
    return (ushort)((u + 0x7fffu + ((u >> 16) & 1u)) >> 16);
}
__device__ __forceinline__ float bf2f_lo(uint32_t d) { return __uint_as_float(d << 16); }
__device__ __forceinline__ float bf2f_hi(uint32_t d) { return __uint_as_float(d & 0xffff0000u); }
__device__ __forceinline__ uint32_t packbf_rhu(float x, float y) {   // round-half-up
    return ((__float_as_uint(x) + 0x8000u) >> 16) |
           ((__float_as_uint(y) + 0x8000u) & 0xffff0000u);
}

// ---------- prep: weights -> bf16 MFMA B-fragment layouts ----------
// frag idx: ((kk*8+nt)*64+lane)*8 + j ; n = nt*16+(lane&15) ; kpos = kk*32+(lane>>4)*8+j
// WCF/WBF use true k = kpos. W2F uses permuted ktrue to match A/B dword packing.
__global__ void prep_kernel(const float* __restrict__ W1, const float* __restrict__ W2,
                            ushort* __restrict__ WCF, ushort* __restrict__ WBF,
                            ushort* __restrict__ W2F) {
    int i = blockIdx.x * blockDim.x + threadIdx.x;
    if (i >= 16384) return;
    int j = i & 7, lf = (i >> 3) & 63, nt = (i >> 9) & 7, kk = i >> 12;
    int n = nt * 16 + (lf & 15);
    int kpos = kk * 32 + ((lf >> 4) << 3) + j;
    int ktrue = (kpos & ~31) | ((kpos >> 1) & 15) | ((kpos & 1) << 4);
    W2F[i] = f2bf_rne(W2[n * 128 + ktrue]);
    float v = (kpos < 64) ? W1[n * 256 + kpos]
                          : W1[n * 256 + 128 + (kpos - 64)] + W1[n * 256 + 192 + (kpos - 64)];
    WCF[i] = f2bf_rne(v);
    if (kk < 2) WBF[i] = f2bf_rne(W1[n * 256 + 64 + kpos]);   // K=64: h1-half only
}

// ---------- node-side: MFMA, register weight frags, direct coalesced stores ----------
__global__ __launch_bounds__(256, 4) void node_kernel(
    const float* __restrict__ h1, const float* __restrict__ h2,
    const ushort* __restrict__ WCF, const ushort* __restrict__ WBF,
    const float* __restrict__ b1,
    uint32_t* __restrict__ Aout, uint32_t* __restrict__ Bout, int N)
{
    __shared__ __align__(16) ushort xt[64 * 136];   // [node][k true order]
    const int tid = threadIdx.x, g = tid >> 6, ln = tid & 63;
    const int nl = ln & 15, q = ln >> 4;
    const int n0 = blockIdx.x * 64;
    const bool full = (n0 + 64 <= N);

    // wave g owns n-cols [g*32, g*32+32): 12 weight frags -> 48 VGPRs
    bf16x8 fa[4][2], fb[2][2];
    #pragma unroll
    for (int kk = 0; kk < 4; ++kk)
        #pragma unroll
        for (int nt = 0; nt < 2; ++nt)
            fa[kk][nt] = *(const bf16x8*)(WCF + (((kk * 8 + g * 2 + nt) * 64 + ln) << 3));
    #pragma unroll
    for (int kk = 0; kk < 2; ++kk)
        #pragma unroll
        for (int nt = 0; nt < 2; ++nt)
            fb[kk][nt] = *(const bf16x8*)(WBF + (((kk * 8 + g * 2 + nt) * 64 + ln) << 3));
    const float b1c0 = b1[g * 32 + nl], b1c1 = b1[g * 32 + 16 + nl];

    // stage X = [h1|h2] as bf16 (true k order)
    #pragma unroll
    for (int i = 0; i < 8; ++i) {
        int local = i * 256 + tid;
        int node = local >> 5;
        int kq = (local & 31) * 4;
        float4 x = make_float4(0.f, 0.f, 0.f, 0.f);
        if (full || n0 + node < N)
            x = (kq < 64) ? *(const float4*)(h1 + (size_t)(n0 + node) * 64 + kq)
                          : *(const float4*)(h2 + (size_t)(n0 + node) * 64 + (kq - 64));
        uint32_t d0 = packbf_rhu(x.x, x.y), d1 = packbf_rhu(x.z, x.w);
        *(uint2*)&xt[node * 136 + kq] = make_uint2(d0, d1);
    }
    __syncthreads();

    #pragma unroll
    for (int m = 0; m < 4; ++m) {
        f32x4 accA[2], accB[2];
        #pragma unroll
        for (int r = 0; r < 4; ++r) { accA[0][r] = accA[1][r] = accB[0][r] = accB[1][r] = 0.f; }
        const ushort* arow = &xt[(m * 16 + nl) * 136 + (q << 3)];
        #pragma unroll
        for (int kk = 0; kk < 4; ++kk) {
            bf16x8 a = *(const bf16x8*)(arow + kk * 32);
            accA[0] = __builtin_amdgcn_mfma_f32_16x16x32_bf16(a, fa[kk][0], accA[0], 0, 0, 0);
            accA[1] = __builtin_amdgcn_mfma_f32_16x16x32_bf16(a, fa[kk][1], accA[1], 0, 0, 0);
            if (kk < 2) {
                accB[0] = __builtin_amdgcn_mfma_f32_16x16x32_bf16(a, fb[kk][0], accB[0], 0, 0, 0);
                accB[1] = __builtin_amdgcn_mfma_f32_16x16x32_bf16(a, fb[kk][1], accB[1], 0, 0, 0);
            }
        }
        // C/D: node = m*16 + q*4 + r, cols (g*32+nl, +16) -> dword slot g*16+nl
        #pragma unroll
        for (int r = 0; r < 4; ++r) {
            int node = n0 + m * 16 + q * 4 + r;
            if (full || node < N) {
                Aout[(size_t)node * 64 + g * 16 + nl] = packbf_rhu(accA[0][r] + b1c0, accA[1][r] + b1c1);
                Bout[(size_t)node * 64 + g * 16 + nl] = packbf_rhu(accB[0][r], accB[1][r]);
            }
        }
    }
}

// ---------- edge-side: pipelined gather + sigmoid + MFMA layer2 + fused layer3 ----------
__global__ __launch_bounds__(256, 4) void edge_kernel(
    const uint32_t* __restrict__ Am, const uint32_t* __restrict__ Bm,
    const int* __restrict__ src, const int* __restrict__ dst,
    const ushort* __restrict__ W2F, const float* __restrict__ b2,
    const float* __restrict__ W3, const float* __restrict__ b3,
    float* __restrict__ out, int E, int ntiles)
{
    __shared__ __align__(16) ushort hlds[2][64 * 136];   // 2 x 17408 B
    __shared__ float part[2][256];
    const int tid = threadIdx.x, g = tid >> 6, ln = tid & 63;
    const int nl = ln & 15, q = ln >> 4;
    const int el = g * 16 + (ln >> 2);   // gather: edge-local for this lane
    const int p  = ln & 3;               // gather: 16B-quad within row

    // register B-frags: this wave's n-quarter (cols g*32..+31), K=128
    bf16x8 bfrag[8];
    #pragma unroll
    for (int kk = 0; kk < 4; ++kk)
        #pragma unroll
        for (int nt = 0; nt < 2; ++nt)
            bfrag[kk * 2 + nt] =
                *(const bf16x8*)(W2F + (((kk * 8 + g * 2 + nt) * 64 + ln) << 3));
    float b2c[2], w3c[2];
    #pragma unroll
    for (int nt = 0; nt < 2; ++nt) {
        int n = g * 32 + nt * 16 + nl;
        b2c[nt] = b2[n]; w3c[nt] = W3[n];
    }
    const float b3c = b3[0];

    uint4 ga[4], gb[4];
    int t = blockIdx.x;
    if (t < ntiles) {   // prologue gather-issue (wave g's 16 edges)
        int eb = t * 64 + g * 16, us = 0, vs = 0;
        if (ln < 16 && eb + ln < E) { us = src[eb + ln]; vs = dst[eb + ln]; }
        int uu = __shfl(us, ln >> 2), vv = __shfl(vs, ln >> 2);
        const uint32_t* ap = Am + (size_t)uu * 64 + p * 4;
        const uint32_t* bp = Bm + (size_t)vv * 64 + p * 4;
        #pragma unroll
        for (int r = 0; r < 4; ++r) {
            ga[r] = *(const uint4*)(ap + r * 16);
            gb[r] = *(const uint4*)(bp + r * 16);
        }
    }
    int buf = 0, prev = -1;
    for (; t < ntiles; t += gridDim.x) {
        // ---- commit gather: sigmoid + pack -> hlds[buf] ----
        #pragma unroll
        for (int r = 0; r < 4; ++r) {
            uint32_t sa[4] = {ga[r].x, ga[r].y, ga[r].z, ga[r].w};
            uint32_t sb[4] = {gb[r].x, gb[r].y, gb[r].z, gb[r].w};
            uint32_t da[4];
            #pragma unroll
            for (int d = 0; d < 4; ++d) {
                float zl = bf2f_lo(sa[d]) + bf2f_lo(sb[d]);
                float zh = bf2f_hi(sa[d]) + bf2f_hi(sb[d]);
                da[d] = packbf_rhu(sigmoid_fast(zl), sigmoid_fast(zh));
            }
            *(uint4*)&hlds[buf][el * 136 + r * 32 + p * 8] =
                make_uint4(da[0], da[1], da[2], da[3]);
        }
        // ---- prefetch next tile's gather ----
        int tn = t + gridDim.x;
        if (tn < ntiles) {
            int eb = tn * 64 + g * 16, us = 0, vs = 0;
            if (ln < 16 && eb + ln < E) { us = src[eb + ln]; vs = dst[eb + ln]; }
            int uu = __shfl(us, ln >> 2), vv = __shfl(vs, ln >> 2);
            const uint32_t* ap = Am + (size_t)uu * 64 + p * 4;
            const uint32_t* bp = Bm + (size_t)vv * 64 + p * 4;
            #pragma unroll
            for (int r = 0; r < 4; ++r) {
                ga[r] = *(const uint4*)(ap + r * 16);
                gb[r] = *(const uint4*)(bp + r * 16);
            }
        }
        __syncthreads();   // hlds[buf] ready; part[buf^1] (prev tile) complete

        // ---- delayed out-write for previous tile ----
        if (prev >= 0 && tid < 64) {
            int e = prev * 64 + tid;
            if (e < E)
                out[e] = (part[buf ^ 1][tid] + part[buf ^ 1][64 + tid])
                       + (part[buf ^ 1][128 + tid] + part[buf ^ 1][192 + tid]) + b3c;
        }

        // ---- MFMA + epilogue -> part[buf] ----
        #pragma unroll
        for (int m = 0; m < 4; ++m) {
            f32x4 acc[2];
            #pragma unroll
            for (int r = 0; r < 4; ++r) { acc[0][r] = 0.f; acc[1][r] = 0.f; }
            const ushort* arow = &hlds[buf][(m * 16 + nl) * 136 + (q << 3)];
            #pragma unroll
            for (int kk = 0; kk < 4; ++kk) {
                bf16x8 a = *(const bf16x8*)(arow + kk * 32);
                acc[0] = __builtin_amdgcn_mfma_f32_16x16x32_bf16(a, bfrag[kk * 2],     acc[0], 0, 0, 0);
                acc[1] = __builtin_amdgcn_mfma_f32_16x16x32_bf16(a, bfrag[kk * 2 + 1], acc[1], 0, 0, 0);
            }
            float pr[4] = {0.f, 0.f, 0.f, 0.f};
            #pragma unroll
            for (int nt = 0; nt < 2; ++nt)
                #pragma unroll
                for (int r = 0; r < 4; ++r)
                    pr[r] = fmaf(w3c[nt], sigmoid_fast(acc[nt][r] + b2c[nt]), pr[r]);
            #pragma unroll
            for (int r = 0; r < 4; ++r) {
                pr[r] += __shfl_xor(pr[r], 1, 16);
                pr[r] += __shfl_xor(pr[r], 2, 16);
                pr[r] += __shfl_xor(pr[r], 4, 16);
                pr[r] += __shfl_xor(pr[r], 8, 16);
            }
            if (nl == 0) {
                #pragma unroll
                for (int r = 0; r < 4; ++r)
                    part[buf][g * 64 + m * 16 + q * 4 + r] = pr[r];
            }
        }
        prev = t; buf ^= 1;
    }
    // ---- drain: out-write for the final tile ----
    __syncthreads();
    if (prev >= 0 && tid < 64) {
        int e = prev * 64 + tid;
        if (e < E)
            out[e] = (part[buf ^ 1][tid] + part[buf ^ 1][64 + tid])
                   + (part[buf ^ 1][128 + tid] + part[buf ^ 1][192 + tid]) + b3c;
    }
}

// ---------- fallback (only if workspace too small) ----------
__global__ void naive_kernel(
    const float* __restrict__ h1, const float* __restrict__ h2,
    const int* __restrict__ src, const int* __restrict__ dst,
    const float* __restrict__ W1, const float* __restrict__ b1,
    const float* __restrict__ W2, const float* __restrict__ b2,
    const float* __restrict__ W3, const float* __restrict__ b3,
    float* __restrict__ out, int E, int N)
{
    int e = blockIdx.x * blockDim.x + threadIdx.x;
    if (e >= E) return;
    int u = src[e], v = dst[e];
    float h[128];
    for (int j = 0; j < 128; ++j) {
        float z = b1[j];
        const float* wj = W1 + j * 256;
        for (int k = 0; k < 64; ++k) {
            z += wj[k] * h1[(size_t)u * 64 + k]
               + wj[64 + k] * h1[(size_t)v * 64 + k]
               + (wj[128 + k] + wj[192 + k]) * h2[(size_t)u * 64 + k];
        }
        h[j] = 1.0f / (1.0f + __expf(-z));
    }
    float gg[128];
    for (int j = 0; j < 128; ++j) {
        float z = b2[j];
        for (int k = 0; k < 128; ++k) z = fmaf(W2[j * 128 + k], h[k], z);
        gg[j] = 1.0f / (1.0f + __expf(-z));
    }
    float s = b3[0];
    for (int j = 0; j < 128; ++j) s = fmaf(W3[j], gg[j], s);
    out[e] = s;
}

extern "C" void kernel_launch(void* const* d_in, const int* in_sizes, int n_in,
                              void* d_out, int out_size, void* d_ws, size_t ws_size,
                              hipStream_t stream) {
    const float* h1 = (const float*)d_in[0];
    const float* h2 = (const float*)d_in[1];
    const int*  src = (const int*)d_in[2];
    const int*  dst = (const int*)d_in[3];
    const float* W1 = (const float*)d_in[4];
    const float* b1 = (const float*)d_in[5];
    const float* W2 = (const float*)d_in[6];
    const float* b2 = (const float*)d_in[7];
    const float* W3 = (const float*)d_in[8];
    const float* b3 = (const float*)d_in[9];
    float* out = (float*)d_out;

    const int N = in_sizes[0] / 64;
    const int E = in_sizes[2];

    // workspace layout (float units)
    size_t offA   = 0;                         // N*64 dwords (bf16-pair packed)
    size_t offB   = offA + (size_t)N * 64;
    size_t offWCF = offB + (size_t)N * 64;     // 16384 ushorts
    size_t offWBF = offWCF + 8192;             // 8192 ushorts
    size_t offW2F = offWBF + 4096;             // 16384 ushorts
    size_t totalF = offW2F + 8192;

    if (ws_size < totalF * sizeof(float)) {
        naive_kernel<<<(E + 255) / 256, 256, 0, stream>>>(
            h1, h2, src, dst, W1, b1, W2, b2, W3, b3, out, E, N);
        return;
    }

    float* ws = (float*)d_ws;
    ushort* WCF = (ushort*)(ws + offWCF);
    ushort* WBF = (ushort*)(ws + offWBF);
    ushort* W2F = (ushort*)(ws + offW2F);

    prep_kernel<<<64, 256, 0, stream>>>(W1, W2, WCF, WBF, W2F);
    node_kernel<<<(N + 63) / 64, 256, 0, stream>>>(
        h1, h2, WCF, WBF, b1, (uint32_t*)(ws + offA), (uint32_t*)(ws + offB), N);
    const int ntiles = (E + 63) / 64;
    edge_kernel<<<2500, 256, 0, stream>>>(
        (const uint32_t*)(ws + offA), (const uint32_t*)(ws + offB), src, dst,
        W2F, b2, W3, b3, out, E, ntiles);
}